// Round 6
// baseline (1762.144 us; speedup 1.0000x reference)
//
#include <hip/hip_runtime.h>
#include <hip/hip_cooperative_groups.h>
#include <math.h>

namespace cg = cooperative_groups;

// Problem constants
#define Bn   32
#define Hn   112
#define Wn   112
#define Cn   256
#define HWn  (Hn * Wn)      // 12544 spatial positions
#define C4   (Cn / 4)       // 64 float4 per position
#define HIDn 32

// ----- fused (cooperative) config -----
#define BCH    8                  // batches per chunk: 8 * 12.85 MB = 102.8 MB << 256 MB L3
#define NCHUNK (Bn / BCH)         // 4 chunks
#define NBF    128                // pool partial blocks per batch
#define POSF   (HWn / NBF)        // 98 positions per block
#define GRIDF  (BCH * NBF)        // 1024 blocks = 4 blocks/CU (co-resident)

// ----- fallback (3-kernel) config -----
#define NB1  32
#define POSB (HWn / NB1)          // 392
#define NB3  98
#define POS3 (HWn / NB3)          // 128

#define NEG_INF (-3.402823466e38f)

typedef float f4 __attribute__((ext_vector_type(4)));

// ===========================================================================
// Fused cooperative kernel: per 8-batch chunk, pool -> grid.sync -> MLP ->
// grid.sync -> scale. The scale pass re-reads the chunk while it is still
// L3-resident, halving HBM read traffic for x.
// ===========================================================================
__global__ __launch_bounds__(256, 4) void fused_kernel(
    const f4* __restrict__ x4,
    const float* __restrict__ w1,   // [Cn][HIDn]
    const float* __restrict__ b1,   // [HIDn]
    const float* __restrict__ w2,   // [HIDn][Cn]
    const float* __restrict__ b2,   // [Cn]
    f4* __restrict__ out4,
    float* __restrict__ psum,       // [Bn][NBF][Cn]
    float* __restrict__ pmax,       // [Bn][NBF][Cn]
    float* __restrict__ scale)      // [Bn][Cn]
{
    cg::grid_group grid = cg::this_grid();

    const int tid     = threadIdx.x;
    const int c4      = tid & 63;        // float4 channel slot
    const int grp     = tid >> 6;        // 0..3 (wave id)
    const int bid     = blockIdx.x;
    const int b_local = bid >> 7;        // 0..7 within chunk
    const int blk     = bid & (NBF - 1); // 0..127 spatial slice

    __shared__ f4 ls[256];
    __shared__ f4 lm[256];
    __shared__ float avg[Cn];
    __shared__ float mx[Cn];
    __shared__ float h2[2][HIDn];

    for (int c = 0; c < NCHUNK; ++c) {
        const int b = c * BCH + b_local;

        // ---------------- phase A: pool partials ----------------
        {
            const f4* base = x4 + ((size_t)b * HWn + (size_t)blk * POSF) * C4;
            f4 s = {0.f, 0.f, 0.f, 0.f};
            f4 m = {NEG_INF, NEG_INF, NEG_INF, NEG_INF};
            #pragma unroll 2
            for (int p = grp; p < POSF; p += 4) {
                f4 v = base[(size_t)p * C4 + c4];
                s += v;
                m.x = fmaxf(m.x, v.x); m.y = fmaxf(m.y, v.y);
                m.z = fmaxf(m.z, v.z); m.w = fmaxf(m.w, v.w);
            }
            ls[tid] = s;
            lm[tid] = m;
            __syncthreads();
            if (tid < 64) {
                f4 s0 = ls[tid], s1 = ls[tid + 64], s2 = ls[tid + 128], s3 = ls[tid + 192];
                f4 m0 = lm[tid], m1 = lm[tid + 64], m2 = lm[tid + 128], m3 = lm[tid + 192];
                f4 so = (s0 + s1) + (s2 + s3);
                f4 mo;
                mo.x = fmaxf(fmaxf(m0.x, m1.x), fmaxf(m2.x, m3.x));
                mo.y = fmaxf(fmaxf(m0.y, m1.y), fmaxf(m2.y, m3.y));
                mo.z = fmaxf(fmaxf(m0.z, m1.z), fmaxf(m2.z, m3.z));
                mo.w = fmaxf(fmaxf(m0.w, m1.w), fmaxf(m2.w, m3.w));
                f4* ps4 = (f4*)(psum + ((size_t)b * NBF + blk) * Cn);
                f4* pm4 = (f4*)(pmax + ((size_t)b * NBF + blk) * Cn);
                // normal stores: phase B re-reads these within microseconds —
                // keep them cache-resident (NT early-evict is wrong here)
                ps4[tid] = so;
                pm4[tid] = mo;
            }
        }

        grid.sync();   // device-scope fence: partials visible to all XCDs

        // ---------------- phase B: finish reduce + MLP + sigmoid ----------------
        if (bid < BCH) {
            const int bb = c * BCH + bid;
            float s = 0.f;
            float m = NEG_INF;
            // latency-critical (only 8 blocks active between two grid syncs):
            // unroll for load-level parallelism
            #pragma unroll 4
            for (int k = 0; k < NBF; ++k) {
                s += psum[((size_t)bb * NBF + k) * Cn + tid];
                m = fmaxf(m, pmax[((size_t)bb * NBF + k) * Cn + tid]);
            }
            avg[tid] = s * (1.0f / (float)HWn);
            mx[tid]  = m;
            __syncthreads();

            if (tid < 64) {
                const int j = tid & 31;
                const int which = tid >> 5;          // 0 = avg, 1 = max
                const float* pool = which ? mx : avg;
                float acc = b1[j];
                #pragma unroll 4
                for (int cc = 0; cc < Cn; ++cc)
                    acc += pool[cc] * w1[cc * HIDn + j];
                h2[which][j] = fmaxf(acc, 0.f);      // relu
            }
            __syncthreads();

            // sigmoid(mlp(avg)+mlp(max)): second layer linear -> b2 twice
            float acc = 2.0f * b2[tid];
            #pragma unroll
            for (int j = 0; j < HIDn; ++j)
                acc += (h2[0][j] + h2[1][j]) * w2[j * Cn + tid];
            scale[(size_t)bb * Cn + tid] = 1.0f / (1.0f + expf(-acc));
        }

        grid.sync();   // scale visible device-wide

        // ---------------- phase C: out = x * scale (x is L3-resident) ----------------
        {
            const f4 sc = ((const f4*)(scale + (size_t)b * Cn))[c4];
            const size_t base = ((size_t)b * HWn + (size_t)blk * POSF) * C4;
            #pragma unroll 2
            for (int p = grp; p < POSF; p += 4) {
                const size_t idx = base + (size_t)p * C4 + c4;
                f4 v = x4[idx];
                v *= sc;
                __builtin_nontemporal_store(v, &out4[idx]);
            }
        }
        // no trailing sync needed: next chunk's pool writes disjoint partials,
        // and the next grid.sync orders everything.
    }
}

// ===========================================================================
// Fallback path (previous verified 3-kernel pipeline, 743 us) — used if ws
// too small or cooperative launch refused.
// ===========================================================================
__global__ __launch_bounds__(256) void pool_kernel(
    const f4* __restrict__ x4,
    float* __restrict__ psum,   // [Bn][NB1][Cn]
    float* __restrict__ pmax)   // [Bn][NB1][Cn]
{
    const int b   = blockIdx.y;
    const int blk = blockIdx.x;
    const int tid = threadIdx.x;
    const int c4  = tid & 63;
    const int grp = tid >> 6;

    const f4* base = x4 + ((size_t)b * HWn + (size_t)blk * POSB) * C4;

    f4 s = {0.f, 0.f, 0.f, 0.f};
    f4 m = {NEG_INF, NEG_INF, NEG_INF, NEG_INF};

    #pragma unroll 2
    for (int p = grp; p < POSB; p += 4) {
        f4 v = base[(size_t)p * C4 + c4];
        s += v;
        m.x = fmaxf(m.x, v.x); m.y = fmaxf(m.y, v.y);
        m.z = fmaxf(m.z, v.z); m.w = fmaxf(m.w, v.w);
    }

    __shared__ f4 ls[256];
    __shared__ f4 lm[256];
    ls[tid] = s;
    lm[tid] = m;
    __syncthreads();

    if (tid < 64) {
        f4 s0 = ls[tid], s1 = ls[tid + 64], s2 = ls[tid + 128], s3 = ls[tid + 192];
        f4 m0 = lm[tid], m1 = lm[tid + 64], m2 = lm[tid + 128], m3 = lm[tid + 192];
        f4 so = (s0 + s1) + (s2 + s3);
        f4 mo;
        mo.x = fmaxf(fmaxf(m0.x, m1.x), fmaxf(m2.x, m3.x));
        mo.y = fmaxf(fmaxf(m0.y, m1.y), fmaxf(m2.y, m3.y));
        mo.z = fmaxf(fmaxf(m0.z, m1.z), fmaxf(m2.z, m3.z));
        mo.w = fmaxf(fmaxf(m0.w, m1.w), fmaxf(m2.w, m3.w));
        f4* ps4 = (f4*)(psum + ((size_t)b * NB1 + blk) * Cn);
        f4* pm4 = (f4*)(pmax + ((size_t)b * NB1 + blk) * Cn);
        __builtin_nontemporal_store(so, &ps4[tid]);
        __builtin_nontemporal_store(mo, &pm4[tid]);
    }
}

__global__ __launch_bounds__(256) void mlp_kernel(
    const float* __restrict__ psum,
    const float* __restrict__ pmax,
    const float* __restrict__ w1,
    const float* __restrict__ b1,
    const float* __restrict__ w2,
    const float* __restrict__ b2,
    float* __restrict__ scale)
{
    const int b   = blockIdx.x;
    const int tid = threadIdx.x;

    __shared__ float avg[Cn];
    __shared__ float mx[Cn];
    __shared__ float h2[2][HIDn];

    float s = 0.f;
    float m = NEG_INF;
    for (int k = 0; k < NB1; ++k) {
        s += psum[((size_t)b * NB1 + k) * Cn + tid];
        m = fmaxf(m, pmax[((size_t)b * NB1 + k) * Cn + tid]);
    }
    avg[tid] = s * (1.0f / (float)HWn);
    mx[tid]  = m;
    __syncthreads();

    if (tid < 64) {
        const int j = tid & 31;
        const int which = tid >> 5;
        const float* pool = which ? mx : avg;
        float acc = b1[j];
        for (int c = 0; c < Cn; ++c)
            acc += pool[c] * w1[c * HIDn + j];
        h2[which][j] = fmaxf(acc, 0.f);
    }
    __syncthreads();

    float acc = 2.0f * b2[tid];
    for (int j = 0; j < HIDn; ++j)
        acc += (h2[0][j] + h2[1][j]) * w2[j * Cn + tid];
    scale[(size_t)b * Cn + tid] = 1.0f / (1.0f + expf(-acc));
}

__global__ __launch_bounds__(256) void scale_kernel(
    const f4* __restrict__ x4,
    const float* __restrict__ scale,
    f4* __restrict__ out4)
{
    const int b   = (Bn - 1)  - (int)blockIdx.y;
    const int blk = (NB3 - 1) - (int)blockIdx.x;
    const int tid = threadIdx.x;
    const int c4  = tid & 63;
    const int grp = tid >> 6;

    const f4 sc = ((const f4*)(scale + (size_t)b * Cn))[c4];
    const size_t base = ((size_t)b * HWn + (size_t)blk * POS3) * C4;

    #pragma unroll 4
    for (int p = grp; p < POS3; p += 4) {
        const size_t idx = base + (size_t)p * C4 + c4;
        f4 v = x4[idx];
        v *= sc;
        __builtin_nontemporal_store(v, &out4[idx]);
    }
}

extern "C" void kernel_launch(void* const* d_in, const int* in_sizes, int n_in,
                              void* d_out, int out_size, void* d_ws, size_t ws_size,
                              hipStream_t stream) {
    const float* x  = (const float*)d_in[0];
    const float* w1 = (const float*)d_in[1];
    const float* b1 = (const float*)d_in[2];
    const float* w2 = (const float*)d_in[3];
    const float* b2 = (const float*)d_in[4];
    float* out = (float*)d_out;

    // ---- fused path: ws layout psum[Bn*NBF*Cn] | pmax[Bn*NBF*Cn] | scale[Bn*Cn]
    const size_t fused_need = ((size_t)2 * Bn * NBF * Cn + (size_t)Bn * Cn) * sizeof(float);
    if (ws_size >= fused_need) {
        float* psum  = (float*)d_ws;
        float* pmax  = psum + (size_t)Bn * NBF * Cn;
        float* scale = pmax + (size_t)Bn * NBF * Cn;

        const f4* x4v = (const f4*)x;
        f4* out4v = (f4*)out;
        void* args[] = {(void*)&x4v, (void*)&w1, (void*)&b1, (void*)&w2, (void*)&b2,
                        (void*)&out4v, (void*)&psum, (void*)&pmax, (void*)&scale};
        hipError_t err = hipLaunchCooperativeKernel((const void*)fused_kernel,
                                                    dim3(GRIDF), dim3(256),
                                                    args, 0, stream);
        if (err == hipSuccess) return;
        (void)hipGetLastError();   // clear sticky error, fall through
    }

    // ---- fallback: verified 3-kernel path (ws layout: psum|pmax [Bn*NB1*Cn], scale)
    float* psum  = (float*)d_ws;
    float* pmax  = psum + (size_t)Bn * NB1 * Cn;
    float* scale = pmax + (size_t)Bn * NB1 * Cn;

    pool_kernel<<<dim3(NB1, Bn), 256, 0, stream>>>((const f4*)x, psum, pmax);
    mlp_kernel<<<Bn, 256, 0, stream>>>(psum, pmax, w1, b1, w2, b2, scale);
    scale_kernel<<<dim3(NB3, Bn), 256, 0, stream>>>((const f4*)x, scale, (f4*)out);
}